// Round 9
// baseline (479.016 us; speedup 1.0000x reference)
//
#include <hip/hip_runtime.h>
#include <hip/hip_bf16.h>
#include <math.h>

#define EPSF 1e-7f

typedef __attribute__((ext_vector_type(8))) short bhalf8;   // 8 bf16 (4 VGPRs)
typedef __attribute__((ext_vector_type(4))) float floatx4;  // MFMA acc

__device__ __forceinline__ void gload_lds16(const void* g, void* l) {
  __builtin_amdgcn_global_load_lds(
      (const __attribute__((address_space(1))) unsigned int*)g,
      (__attribute__((address_space(3))) unsigned int*)l,
      16, 0, 0);
}

// ============================================================================
// conv1: x[1024,3,32,32] -> h1t[1024,225,128] bf16 (position-major, ic inner)
// ============================================================================
__global__ __launch_bounds__(256) void conv1_kernel(
    const float* __restrict__ x, const float* __restrict__ w,
    const float* __restrict__ bias, __hip_bfloat16* __restrict__ out)
{
  __shared__ float wl[3456];     // [128 oc][27 taps]
  __shared__ float bl[128];
  const int b = blockIdx.x;
  const int t = threadIdx.x;
  for (int i = t; i < 3456; i += 256) wl[i] = w[i];
  if (t < 128) bl[t] = bias[t];
  __syncthreads();
  if (t >= 225) return;
  const int py = t / 15, px = t % 15;
  const float* xb = x + b * 3072;
  float win[27];
#pragma unroll
  for (int c = 0; c < 3; ++c)
#pragma unroll
    for (int ky = 0; ky < 3; ++ky)
#pragma unroll
      for (int kx = 0; kx < 3; ++kx)
        win[c*9 + ky*3 + kx] = xb[c*1024 + (py*2 + ky)*32 + (px*2 + kx)];
#pragma unroll 1
  for (int oc0 = 0; oc0 < 128; oc0 += 32) {
    __hip_bfloat16 hv[32];
#pragma unroll
    for (int oc = 0; oc < 32; ++oc) {
      const float* wp = &wl[(oc0 + oc)*27];
      float acc = bl[oc0 + oc];
#pragma unroll
      for (int q = 0; q < 27; ++q) acc = fmaf(win[q], wp[q], acc);
      hv[oc] = __float2bfloat16(fmaxf(acc, 0.f));
    }
    uint4* dst = (uint4*)&out[((size_t)b*225 + t)*128 + oc0];
    const uint4* src = (const uint4*)hv;
#pragma unroll
    for (int q = 0; q < 4; ++q) dst[q] = src[q];
  }
}

// ============================================================================
// wtrans2: conv2_w -> dense step-major bf16 wt2[s][oc][kq'], s = 32-k step,
// with 16B-chunk swizzle c = c' ^ ((oc>>1)&3) baked in so the lane-linear
// global_load_lds image gives 2-way-max (free) LDS B reads.
// ============================================================================
__global__ __launch_bounds__(256) void wtrans_kernel(
    const float* __restrict__ w, __hip_bfloat16* __restrict__ wt)
{
  int i = blockIdx.x*256 + threadIdx.x;          // 819,200 total
  int s = i >> 13, r = i & 8191;
  int oc = r >> 5, kq = r & 31;
  int cp = kq >> 3, e = kq & 7;                  // stored chunk, elem
  int c  = cp ^ ((oc >> 1) & 3);                 // logical chunk
  int k  = s*32 + c*8 + e;
  int tap = k >> 7, ic = k & 127;
  wt[i] = __float2bfloat16(w[(oc*128 + ic)*25 + tap]);
}

// ============================================================================
// wtrans3: conv3_w -> dense step-major bf16 wt3[s][oc][kq'], s = 64-k step,
// chunk swizzle c = c' ^ (oc&7) (8 chunks/row) -> 2-way-max LDS B reads.
// ============================================================================
__global__ __launch_bounds__(256) void wtrans3_kernel(
    const float* __restrict__ w, __hip_bfloat16* __restrict__ wt)
{
  int i = blockIdx.x*256 + threadIdx.x;          // 1,638,400 total
  int s = i >> 14, r = i & 16383;
  int oc = r >> 6, kq = r & 63;
  int cp = kq >> 3, e = kq & 7;
  int c  = cp ^ (oc & 7);
  int k  = s*64 + c*8 + e;
  int tap = k >> 8, ic = k & 255;
  wt[i] = __float2bfloat16(w[(oc*256 + ic)*25 + tap]);
}

// ============================================================================
// wtrans_caps: caps_w fp32 [i][o][k][j] -> cwt BF16 [i][o][j][k] (k contig)
// ============================================================================
__global__ __launch_bounds__(256) void wtrans_caps_kernel(
    const float* __restrict__ cw, __hip_bfloat16* __restrict__ cwt)
{
  int i2 = blockIdx.x*256 + threadIdx.x;         // 163,840 total
  int k  = i2 & 15, j = (i2 >> 4) & 15, io = i2 >> 8;
  cwt[i2] = __float2bfloat16(cw[(io*16 + k)*16 + j]);
}

// ============================================================================
// wtrans_fc1: fc1_w [512][160] -> fc1wt [160][512] (coalesced caps epilogue)
// ============================================================================
__global__ __launch_bounds__(256) void wtrans_fc1_kernel(
    const float* __restrict__ w, float* __restrict__ wt)
{
  int i = blockIdx.x*256 + threadIdx.x;          // 81,920 total
  int j = i >> 9, n = i & 511;
  wt[i] = w[n*160 + j];
}

// ============================================================================
// cast: fp32 -> bf16 elementwise, for fc weights
// ============================================================================
__global__ __launch_bounds__(256) void cast_bf16_kernel(
    const float* __restrict__ src, __hip_bfloat16* __restrict__ dst, int n)
{
  int i = blockIdx.x*256 + threadIdx.x;
  if (i < n) dst[i] = __float2bfloat16(src[i]);
}

// ============================================================================
// conv2_mfma: h1t[1024,225,128]bf16 -> h2t[1024,36,256]bf16, 5x5 s2, ReLU
// M=72 (2 img), N=256, K=3200. 512 thr = 8 waves.
// R9: B via global_load_lds double-buffer (16KB/step, dense+swizzled wt2),
// one barrier/step. R8 register distance-4 was collapsed by the compiler
// (VGPR=52 on conv3) -> full per-step latency exposure; DMA staging is the
// compiler-robust pipeline.
// ============================================================================
__global__ __launch_bounds__(512) void conv2_mfma_kernel(
    const __hip_bfloat16* __restrict__ a,   // h1t [1024][225][128]
    const __hip_bfloat16* __restrict__ wt,  // wt2 dense [100][256][32']
    const float* __restrict__ bias,
    __hip_bfloat16* __restrict__ out)       // h2t [1024][36][256]
{
  __shared__ __align__(16) unsigned short Il[2*225*136];  // 122,400 B
  __shared__ uint4 Bl[2048];                              //  32,768 B (2x16K)
  const int b0   = blockIdx.x * 2;
  const int t    = threadIdx.x;
  const int lane = t & 63;
  const int w    = t >> 6;        // 0..7
  const int n    = lane & 15;
  const int g    = lane >> 4;

  const char* gW = (const char*)wt;
  char* BlB = (char*)Bl;

  // ---- stage step 0 -> buf 0 (2 x 16B per thread, lane-linear) ----
#pragma unroll
  for (int j = 0; j < 2; ++j)
    gload_lds16(gW + j*8192 + t*16, BlB + j*8192 + t*16);

  // ---- stage 2 images: chunk c of pixel p -> slot (c + p/2 + p/32)&15 ----
  for (int i = t; i < 7200; i += 512) {
    int img = (i >= 3600);
    int r = i - img*3600;
    int p = r >> 4, c = r & 15;
    uint4 v = *(const uint4*)((const char*)a +
              (((size_t)(b0+img)*225 + p)*256 + c*16));
    int csw = (c + (p >> 1) + (p >> 5)) & 15;
    *(uint4*)((char*)Il + ((img*225 + p)*136 + csw*8)*2) = v;
  }

  // ---- per-lane M geometry ----
  int rowb[5], pixb[5];
#pragma unroll
  for (int mt = 0; mt < 5; ++mt) {
    int m  = mt*16 + n;
    int mm = (m < 72) ? m : 0;
    int img = (mm >= 36);
    int pos = mm - img*36;
    int py = pos/6, px = pos - py*6;
    pixb[mt] = 30*py + 2*px;
    rowb[mt] = img*225*136;
  }
  // B LDS read offsets (within buffer): oc*64 + (g ^ ((n>>1)&3))*16
  int Boff[2];
#pragma unroll
  for (int nt = 0; nt < 2; ++nt)
    Boff[nt] = (w*32 + nt*16 + n)*64 + ((g ^ ((n >> 1) & 3))*16);

  floatx4 acc[5][2];
#pragma unroll
  for (int mt = 0; mt < 5; ++mt)
#pragma unroll
    for (int nt = 0; nt < 2; ++nt)
      acc[mt][nt] = (floatx4){0.f, 0.f, 0.f, 0.f};

  __syncthreads();   // Il + buf0 staged

  int s = 0;
#pragma unroll 1
  for (int ky = 0; ky < 5; ++ky) {
#pragma unroll 1
    for (int kx = 0; kx < 5; ++kx) {
      const int dpix = ky*15 + kx;
      int prow[5], pqv[5];
#pragma unroll
      for (int mt = 0; mt < 5; ++mt) {
        int p = pixb[mt] + dpix;
        prow[mt] = rowb[mt] + p*136;
        pqv[mt]  = (p >> 1) + (p >> 5);
      }
#pragma unroll
      for (int icq = 0; icq < 4; ++icq) {
        const int scur = s + icq;
        // stage step scur+1 into the other buffer
        if (scur < 99) {
          const char* gsrc = gW + (size_t)(scur+1)*16384 + t*16;
          char* ldst = BlB + ((scur+1)&1)*16384 + t*16;
          gload_lds16(gsrc,        ldst);
          gload_lds16(gsrc + 8192, ldst + 8192);
        }
        // B fragments from current buffer
        const char* bp = BlB + (scur&1)*16384;
        bhalf8 bf[2];
#pragma unroll
        for (int nt = 0; nt < 2; ++nt)
          bf[nt] = *(const bhalf8*)(bp + Boff[nt]);
        // A fragments + MFMA
#pragma unroll
        for (int mt = 0; mt < 5; ++mt) {
          int csw = ((icq*4 + g) + pqv[mt]) & 15;
          bhalf8 af = *(const bhalf8*)((const char*)Il +
                       (prow[mt] + csw*8)*2);
#pragma unroll
          for (int nt = 0; nt < 2; ++nt)
            acc[mt][nt] = __builtin_amdgcn_mfma_f32_16x16x32_bf16(
                af, bf[nt], acc[mt][nt], 0, 0, 0);
        }
        __syncthreads();
      }
      s += 4;
    }
  }

  // ---- epilogue: D row=g*4+r (m), col=n (oc). write bf16 [img][pos][oc] ----
  float bv[2];
#pragma unroll
  for (int nt = 0; nt < 2; ++nt) bv[nt] = bias[w*32 + nt*16 + n];
#pragma unroll
  for (int mt = 0; mt < 5; ++mt) {
#pragma unroll
    for (int r = 0; r < 4; ++r) {
      int m = mt*16 + g*4 + r;
      if (m < 72) {
        int img = (m >= 36);
        int pos = m - img*36;
        __hip_bfloat16* op = out + (((size_t)(b0+img)*36 + pos)*256 + w*32 + n);
#pragma unroll
        for (int nt = 0; nt < 2; ++nt)
          op[nt*16] = __float2bfloat16(fmaxf(acc[mt][nt][r] + bv[nt], 0.f));
      }
    }
  }
}

// ============================================================================
// conv3_mfma: h2t[1024,36,256]bf16 -> h3[1024,256,2,2]fp32, 5x5 s1, ReLU
// M=16 (4 img), N=256, K=6400. 512 thr = 8 waves.
// R9: B via global_load_lds double-buffer (32KB/step), swizzled dense wt3.
// ============================================================================
__global__ __launch_bounds__(512) void conv3_mfma_kernel(
    const __hip_bfloat16* __restrict__ a,   // h2t [1024][36][256]
    const __hip_bfloat16* __restrict__ wt,  // wt3 dense [100][256][64']
    const float* __restrict__ bias,
    float* __restrict__ out)                // h3 [1024][256][4]
{
  __shared__ __align__(16) unsigned short Il[4*10072];    // 80,576 B
  __shared__ uint4 Bl[4096];                              // 65,536 B (2x32K)
  const int b0   = blockIdx.x * 4;
  const int t    = threadIdx.x;
  const int lane = t & 63;
  const int w    = t >> 6;        // 0..7
  const int n    = lane & 15;
  const int g    = lane >> 4;

  const char* gW = (const char*)wt;
  char* BlB = (char*)Bl;

  // ---- stage step 0 -> buf 0 (4 x 16B per thread) ----
#pragma unroll
  for (int j = 0; j < 4; ++j)
    gload_lds16(gW + j*8192 + t*16, BlB + j*8192 + t*16);

  // ---- stage 4 input images: [pix][256ic] -> LDS [pix][272pad] ----
  for (int i = t; i < 4608; i += 512) {
    int img = i / 1152, r = i - img*1152;
    int p = r >> 5, c = r & 31;
    uint4 v = *(const uint4*)((const char*)a +
              ((((size_t)(b0+img)*36 + p) << 9) + c*16));
    *(uint4*)((char*)Il + img*20144 + p*544 + c*16) = v;
  }

  int Abase;
  {
    int img = n >> 2, pos = n & 3;
    int py = pos >> 1, px = pos & 1;
    Abase = img*20144 + (py*6 + px)*544 + g*16;       // bytes
  }
  // B LDS read offsets: oc*128 + ((h*4+g) ^ (n&7))*16
  int Boff[2][2];
#pragma unroll
  for (int nt = 0; nt < 2; ++nt)
#pragma unroll
    for (int h = 0; h < 2; ++h)
      Boff[nt][h] = (w*32 + nt*16 + n)*128 + (((h*4 + g) ^ (n & 7))*16);

  floatx4 acc[2];
#pragma unroll
  for (int nt = 0; nt < 2; ++nt) acc[nt] = (floatx4){0.f, 0.f, 0.f, 0.f};

  __syncthreads();   // Il + buf0 staged

  int s = 0;
#pragma unroll 1
  for (int ky = 0; ky < 5; ++ky) {
#pragma unroll 1
    for (int kx = 0; kx < 5; ++kx) {
      const int tapoff = (ky*6 + kx) * 544;
      const char* ap = (const char*)Il + Abase + tapoff;
#pragma unroll
      for (int ip = 0; ip < 4; ++ip) {
        const int scur = s + ip;
        if (scur < 99) {
          const char* gsrc = gW + (size_t)(scur+1)*32768 + t*16;
          char* ldst = BlB + ((scur+1)&1)*32768 + t*16;
#pragma unroll
          for (int j = 0; j < 4; ++j)
            gload_lds16(gsrc + j*8192, ldst + j*8192);
        }
        const char* bp = BlB + (scur&1)*32768;
        bhalf8 a0 = *(const bhalf8*)(ap + ip*128);
        bhalf8 a1 = *(const bhalf8*)(ap + ip*128 + 64);
#pragma unroll
        for (int nt = 0; nt < 2; ++nt) {
          bhalf8 b0 = *(const bhalf8*)(bp + Boff[nt][0]);
          bhalf8 b1 = *(const bhalf8*)(bp + Boff[nt][1]);
          acc[nt] = __builtin_amdgcn_mfma_f32_16x16x32_bf16(
              a0, b0, acc[nt], 0, 0, 0);
          acc[nt] = __builtin_amdgcn_mfma_f32_16x16x32_bf16(
              a1, b1, acc[nt], 0, 0, 0);
        }
        __syncthreads();
      }
      s += 4;
    }
  }

  // ---- epilogue ----
  float bv[2];
#pragma unroll
  for (int nt = 0; nt < 2; ++nt) bv[nt] = bias[w*32 + nt*16 + n];
#pragma unroll
  for (int r = 0; r < 4; ++r) {
    int m = g*4 + r;
    int img = m >> 2, pos = m & 3;
    float* op = out + (((size_t)(b0+img)*256 + w*32 + n)*4 + pos);
#pragma unroll
    for (int nt = 0; nt < 2; ++nt)
      op[nt*64] = fmaxf(acc[nt][r] + bv[nt], 0.f);
  }
}

// ============================================================================
// caps: squash -> u_hat -> 3x routing -> v_lengths + fused fc1
// ============================================================================
__global__ __launch_bounds__(256) void caps_kernel(
    const float* __restrict__ h3, const __hip_bfloat16* __restrict__ cwt,
    const float* __restrict__ cb, const int* __restrict__ y,
    const float* __restrict__ fc1wt, const float* __restrict__ fc1b,
    float* __restrict__ vlen, __hip_bfloat16* __restrict__ h1f)
{
  __shared__ float prim[1024];     // [64][16]
  __shared__ float uh[10240];      // [64][10][16]
  __shared__ float bij[640];
  __shared__ float cij[640];
  __shared__ float vv[160];        // [10][16]
  const int b = blockIdx.x, t = threadIdx.x;
  {
    const int cap = t >> 2, part = t & 3;
    float4 h = *(const float4*)&h3[b*1024 + cap*16 + part*4];
    float d = h.x*h.x + h.y*h.y + h.z*h.z + h.w*h.w;
    d += __shfl_xor(d, 1);
    d += __shfl_xor(d, 2);
    float sc = d / (1.f + d) / sqrtf(d + EPSF);
    float4 o4 = make_float4(h.x*sc, h.y*sc, h.z*sc, h.w*sc);
    *(float4*)&prim[cap*16 + part*4] = o4;
  }
  for (int f = t; f < 640; f += 256) bij[f] = 0.f;
  __syncthreads();
  for (int f = t; f < 10240; f += 256) {
    const int i = f / 160;
    const uint4* wv = (const uint4*)(cwt + (size_t)f*16);
    uint4 wa = wv[0], wb = wv[1];
    unsigned uw[8] = {wa.x, wa.y, wa.z, wa.w, wb.x, wb.y, wb.z, wb.w};
    const float* pp = prim + i*16;
    float s = 0.f;
#pragma unroll
    for (int q = 0; q < 8; ++q) {
      float lo = __uint_as_float(uw[q] << 16);
      float hi = __uint_as_float(uw[q] & 0xffff0000u);
      s = fmaf(pp[2*q],   lo, s);
      s = fmaf(pp[2*q+1], hi, s);
    }
    uh[f] = s;
  }
  __syncthreads();
  for (int r = 0; r < 3; ++r) {
    if (t < 64) {
      float e[10];
      float mx = -1e30f;
#pragma unroll
      for (int o = 0; o < 10; ++o) { e[o] = bij[t*10 + o]; mx = fmaxf(mx, e[o]); }
      float sum = 0.f;
#pragma unroll
      for (int o = 0; o < 10; ++o) { e[o] = expf(e[o] - mx); sum += e[o]; }
      float inv = 1.f / sum;
#pragma unroll
      for (int o = 0; o < 10; ++o) cij[t*10 + o] = e[o] * inv;
    }
    __syncthreads();
    if (t < 160) {
      const int o = t >> 4;
      float s = cb[t];
      for (int i = 0; i < 64; ++i) s = fmaf(cij[i*10 + o], uh[i*160 + t], s);
      float d = s*s;
      d += __shfl_xor(d, 1); d += __shfl_xor(d, 2);
      d += __shfl_xor(d, 4); d += __shfl_xor(d, 8);
      float sc = d / (1.f + d) / sqrtf(d + EPSF);
      vv[t] = s * sc;
      if (r == 2 && (t & 15) == 0)
        vlen[b*10 + o] = sqrtf(sc*sc*d + EPSF);
    }
    __syncthreads();
    if (r < 2) {
      for (int f = t; f < 640; f += 256) {
        int i = f / 10, o = f % 10;
        const float* up = &uh[i*160 + o*16];
        const float* vp = &vv[o*16];
        float a = 0.f;
#pragma unroll
        for (int j = 0; j < 16; ++j) a = fmaf(up[j], vp[j], a);
        bij[f] += a;
      }
      __syncthreads();
    }
  }
  const int yb = y[b];
  const float* vy = &vv[yb*16];
  for (int nn = t; nn < 512; nn += 256) {
    float s = fc1b[nn];
#pragma unroll
    for (int k = 0; k < 16; ++k)
      s = fmaf(vy[k], fc1wt[(yb*16 + k)*512 + nn], s);   // coalesced rows
    h1f[b*512 + nn] = __float2bfloat16(fmaxf(s, 0.f));
  }
}

// ============================================================================
// fc_mfma: out = act(A[M,K]bf16 @ W[N,K]bf16^T + bias). Pure-register GEMM,
// two statically-indexed register sets (R5 scratch-demotion lesson).
// ============================================================================
template<int ACT, int MT, int NT>
__global__ __launch_bounds__(256) void fc_mfma_kernel(
    const __hip_bfloat16* __restrict__ A,   // [M,K]
    const __hip_bfloat16* __restrict__ W,   // [N,K]
    const float* __restrict__ bias,
    void* __restrict__ outv, int M, int N, int K)
{
  const int t    = threadIdx.x;
  const int lane = t & 63;
  const int w    = t >> 6;
  const int wr   = w >> 1, wc = w & 1;
  const int n    = lane & 15, g = lane >> 4;
  const int m0   = blockIdx.x * (2*MT*16) + wr*(MT*16);
  const int n0   = blockIdx.y * (2*NT*16) + wc*(NT*16);
  const __hip_bfloat16* Ap = A + (size_t)(m0 + n)*K + g*8;
  const __hip_bfloat16* Wp = W + (size_t)(n0 + n)*K + g*8;
  const int steps = K >> 5;

  bhalf8 aa0[MT], aa1[MT], bb0[NT], bb1[NT];
#pragma unroll
  for (int mt = 0; mt < MT; ++mt) {
    aa0[mt] = *(const bhalf8*)(Ap + (size_t)mt*16*K);
    aa1[mt] = *(const bhalf8*)(Ap + (size_t)mt*16*K + 32);
  }
#pragma unroll
  for (int nt = 0; nt < NT; ++nt) {
    bb0[nt] = *(const bhalf8*)(Wp + (size_t)nt*16*K);
    bb1[nt] = *(const bhalf8*)(Wp + (size_t)nt*16*K + 32);
  }

  floatx4 acc[MT][NT];
#pragma unroll
  for (int mt = 0; mt < MT; ++mt)
#pragma unroll
    for (int nt = 0; nt < NT; ++nt)
      acc[mt][nt] = (floatx4){0.f, 0.f, 0.f, 0.f};

#pragma unroll 1
  for (int s = 0; s < steps; s += 2) {
#pragma unroll
    for (int mt = 0; mt < MT; ++mt)
#pragma unroll
      for (int nt = 0; nt < NT; ++nt)
        acc[mt][nt] = __builtin_amdgcn_mfma_f32_16x16x32_bf16(
            aa0[mt], bb0[nt], acc[mt][nt], 0, 0, 0);
    {
      const int spre = (s + 2 < steps) ? (s + 2) : s;
#pragma unroll
      for (int mt = 0; mt < MT; ++mt)
        aa0[mt] = *(const bhalf8*)(Ap + (size_t)mt*16*K + spre*32);
#pragma unroll
      for (int nt = 0; nt < NT; ++nt)
        bb0[nt] = *(const bhalf8*)(Wp + (size_t)nt*16*K + spre*32);
    }
#pragma unroll
    for (int mt = 0; mt < MT; ++mt)
#pragma unroll
      for (int nt = 0; nt < NT; ++nt)
        acc[mt][nt] = __builtin_amdgcn_mfma_f32_16x16x32_bf16(
            aa1[mt], bb1[nt], acc[mt][nt], 0, 0, 0);
    {
      const int spre = (s + 3 < steps) ? (s + 3) : (s + 1);
#pragma unroll
      for (int mt = 0; mt < MT; ++mt)
        aa1[mt] = *(const bhalf8*)(Ap + (size_t)mt*16*K + spre*32);
#pragma unroll
      for (int nt = 0; nt < NT; ++nt)
        bb1[nt] = *(const bhalf8*)(Wp + (size_t)nt*16*K + spre*32);
    }
  }

  // epilogue: D row = g*4+r, col = n
#pragma unroll
  for (int mt = 0; mt < MT; ++mt) {
#pragma unroll
    for (int r = 0; r < 4; ++r) {
      const int m = m0 + mt*16 + g*4 + r;
#pragma unroll
      for (int nt = 0; nt < NT; ++nt) {
        const int col = n0 + nt*16 + n;
        float v = acc[mt][nt][r] + bias[col];
        if (ACT == 0) {
          ((__hip_bfloat16*)outv)[(size_t)m*N + col] =
              __float2bfloat16(fmaxf(v, 0.f));
        } else {
          ((float*)outv)[(size_t)m*N + col] = 1.f / (1.f + expf(-v));
        }
      }
    }
  }
}

// ============================================================================
extern "C" void kernel_launch(void* const* d_in, const int* in_sizes, int n_in,
                              void* d_out, int out_size, void* d_ws, size_t ws_size,
                              hipStream_t stream) {
  const float* x       = (const float*)d_in[0];
  const int*   y       = (const int*)  d_in[1];
  const float* conv1_w = (const float*)d_in[2];
  const float* conv1_b = (const float*)d_in[3];
  const float* conv2_w = (const float*)d_in[4];
  const float* conv2_b = (const float*)d_in[5];
  const float* conv3_w = (const float*)d_in[6];
  const float* conv3_b = (const float*)d_in[7];
  const float* caps_w  = (const float*)d_in[8];
  const float* caps_b  = (const float*)d_in[9];
  const float* fc1_w   = (const float*)d_in[10];
  const float* fc1_b   = (const float*)d_in[11];
  const float* fc2_w   = (const float*)d_in[12];
  const float* fc2_b   = (const float*)d_in[13];
  const float* fc3_w   = (const float*)d_in[14];
  const float* fc3_b   = (const float*)d_in[15];
  float* out = (float*)d_out;
  float* ws  = (float*)d_ws;

  // ws layout (float units), total 24,526,848 floats = 98.1 MB
  __hip_bfloat16* h1t   = (__hip_bfloat16*)ws;                // 29,491,200 bf16
  __hip_bfloat16* wt2   = (__hip_bfloat16*)(ws + 14745600);   //    819,200 bf16
  __hip_bfloat16* wt3   = (__hip_bfloat16*)(ws + 15155200);   //  1,638,400 bf16
  __hip_bfloat16* h2t   = (__hip_bfloat16*)(ws + 15974400);   //  9,437,184 bf16
  float*          h3c   = ws + 20692992;                      //  1,048,576 f32
  __hip_bfloat16* h1f   = (__hip_bfloat16*)(ws + 21741568);   //    524,288 bf16
  __hip_bfloat16* h2f   = (__hip_bfloat16*)(ws + 22003712);   //  1,048,576 bf16
  __hip_bfloat16* wf2   = (__hip_bfloat16*)(ws + 22528000);   //    524,288 bf16
  __hip_bfloat16* wf3   = (__hip_bfloat16*)(ws + 22790144);   //  3,145,728 bf16
  __hip_bfloat16* cwt   = (__hip_bfloat16*)(ws + 24363008);   //    163,840 bf16
  float*          fc1wt = ws + 24444928;                      //     81,920 f32

  wtrans_kernel     <<<dim3(3200),  256, 0, stream>>>(conv2_w, wt2);
  wtrans3_kernel    <<<dim3(6400),  256, 0, stream>>>(conv3_w, wt3);
  wtrans_caps_kernel<<<dim3(640),   256, 0, stream>>>(caps_w, cwt);
  wtrans_fc1_kernel <<<dim3(320),   256, 0, stream>>>(fc1_w, fc1wt);
  cast_bf16_kernel  <<<dim3(2048),  256, 0, stream>>>(fc2_w, wf2, 524288);
  cast_bf16_kernel  <<<dim3(12288), 256, 0, stream>>>(fc3_w, wf3, 3145728);
  conv1_kernel<<<dim3(1024),      256, 0, stream>>>(x, conv1_w, conv1_b, h1t);
  conv2_mfma_kernel<<<dim3(512),  512, 0, stream>>>(h1t, wt2, conv2_b, h2t);
  conv3_mfma_kernel<<<dim3(256),  512, 0, stream>>>(h2t, wt3, conv3_b, h3c);
  caps_kernel<<<dim3(1024),       256, 0, stream>>>(h3c, cwt, caps_b, y,
                                                    fc1wt, fc1_b, out, h1f);
  fc_mfma_kernel<0,2,2><<<dim3(16, 16), 256, 0, stream>>>(
      h1f, wf2, fc2_b, h2f, 1024, 1024, 512);
  fc_mfma_kernel<1,2,2><<<dim3(16, 48), 256, 0, stream>>>(
      h2f, wf3, fc3_b, out + 10240, 1024, 3072, 1024);
}

// Round 10
// 372.556 us; speedup vs baseline: 1.2858x; 1.2858x over previous
//
#include <hip/hip_runtime.h>
#include <hip/hip_bf16.h>
#include <math.h>

#define EPSF 1e-7f

typedef __attribute__((ext_vector_type(8))) short bhalf8;   // 8 bf16 (4 VGPRs)
typedef __attribute__((ext_vector_type(4))) float floatx4;  // MFMA acc

// ============================================================================
// conv1: x[1024,3,32,32] -> h1t[1024,225,128] bf16 (position-major, ic inner)
// ============================================================================
__global__ __launch_bounds__(256) void conv1_kernel(
    const float* __restrict__ x, const float* __restrict__ w,
    const float* __restrict__ bias, __hip_bfloat16* __restrict__ out)
{
  __shared__ float wl[3456];     // [128 oc][27 taps]
  __shared__ float bl[128];
  const int b = blockIdx.x;
  const int t = threadIdx.x;
  for (int i = t; i < 3456; i += 256) wl[i] = w[i];
  if (t < 128) bl[t] = bias[t];
  __syncthreads();
  if (t >= 225) return;
  const int py = t / 15, px = t % 15;
  const float* xb = x + b * 3072;
  float win[27];
#pragma unroll
  for (int c = 0; c < 3; ++c)
#pragma unroll
    for (int ky = 0; ky < 3; ++ky)
#pragma unroll
      for (int kx = 0; kx < 3; ++kx)
        win[c*9 + ky*3 + kx] = xb[c*1024 + (py*2 + ky)*32 + (px*2 + kx)];
#pragma unroll 1
  for (int oc0 = 0; oc0 < 128; oc0 += 32) {
    __hip_bfloat16 hv[32];
#pragma unroll
    for (int oc = 0; oc < 32; ++oc) {
      const float* wp = &wl[(oc0 + oc)*27];
      float acc = bl[oc0 + oc];
#pragma unroll
      for (int q = 0; q < 27; ++q) acc = fmaf(win[q], wp[q], acc);
      hv[oc] = __float2bfloat16(fmaxf(acc, 0.f));
    }
    uint4* dst = (uint4*)&out[((size_t)b*225 + t)*128 + oc0];
    const uint4* src = (const uint4*)hv;
#pragma unroll
    for (int q = 0; q < 4; ++q) dst[q] = src[q];
  }
}

// ============================================================================
// wtrans2: conv2_w -> dense step-major bf16 wt2[s][oc][kq] (R8 plain form —
// register B loads need logical k order, no swizzle bake)
// ============================================================================
__global__ __launch_bounds__(256) void wtrans_kernel(
    const float* __restrict__ w, __hip_bfloat16* __restrict__ wt)
{
  int i = blockIdx.x*256 + threadIdx.x;          // 819,200 total
  int s = i >> 13, r = i & 8191;
  int oc = r >> 5, kq = r & 31;
  int k = s*32 + kq;
  int tap = k >> 7, ic = k & 127;
  wt[i] = __float2bfloat16(w[(oc*128 + ic)*25 + tap]);
}

// ============================================================================
// wtrans3: conv3_w -> dense step-major bf16 wt3[s][oc][kq], s = 64-k step
// (plain; split-K slices map to s' = tap*4 + kq/2, offset (kq&1)*32)
// ============================================================================
__global__ __launch_bounds__(256) void wtrans3_kernel(
    const float* __restrict__ w, __hip_bfloat16* __restrict__ wt)
{
  int i = blockIdx.x*256 + threadIdx.x;          // 1,638,400 total
  int s = i >> 14, r = i & 16383;
  int oc = r >> 6, kq = r & 63;
  int k = s*64 + kq;
  int tap = k >> 8, ic = k & 255;
  wt[i] = __float2bfloat16(w[(oc*256 + ic)*25 + tap]);
}

// ============================================================================
// wtrans_caps: caps_w fp32 [i][o][k][j] -> cwt BF16 [i][o][j][k] (k contig)
// ============================================================================
__global__ __launch_bounds__(256) void wtrans_caps_kernel(
    const float* __restrict__ cw, __hip_bfloat16* __restrict__ cwt)
{
  int i2 = blockIdx.x*256 + threadIdx.x;         // 163,840 total
  int k  = i2 & 15, j = (i2 >> 4) & 15, io = i2 >> 8;
  cwt[i2] = __float2bfloat16(cw[(io*16 + k)*16 + j]);
}

// ============================================================================
// wtrans_fc1: fc1_w [512][160] -> fc1wt [160][512]
// ============================================================================
__global__ __launch_bounds__(256) void wtrans_fc1_kernel(
    const float* __restrict__ w, float* __restrict__ wt)
{
  int i = blockIdx.x*256 + threadIdx.x;          // 81,920 total
  int j = i >> 9, n = i & 511;
  wt[i] = w[n*160 + j];
}

// ============================================================================
// cast: fp32 -> bf16 elementwise
// ============================================================================
__global__ __launch_bounds__(256) void cast_bf16_kernel(
    const float* __restrict__ src, __hip_bfloat16* __restrict__ dst, int n)
{
  int i = blockIdx.x*256 + threadIdx.x;
  if (i < n) dst[i] = __float2bfloat16(src[i]);
}

// ============================================================================
// conv2_mfma: h1t -> h2t bf16, 5x5 s2, ReLU. M=72 (2 img), N=256, K=3200.
// R10: 1024 threads = 16 waves = 4 waves/SIMD (R9 lesson: barrier-per-step
// drains kill it; R4/R8 lesson: register pipeline needs TLP to hide L2).
// Wave w owns 16 oc (1 Nt); B register distance-4 (bb[4], static idx);
// A input-stationary LDS with conflict-free chunk swizzle. No K-loop barrier.
// ============================================================================
__global__ __launch_bounds__(1024) void conv2_mfma_kernel(
    const __hip_bfloat16* __restrict__ a,   // h1t [1024][225][128]
    const __hip_bfloat16* __restrict__ wt,  // wt2 dense [100][256][32]
    const float* __restrict__ bias,
    __hip_bfloat16* __restrict__ out)       // h2t [1024][36][256]
{
  __shared__ __align__(16) unsigned short Il[2*225*136];  // 122,400 B
  const int b0   = blockIdx.x * 2;
  const int t    = threadIdx.x;
  const int lane = t & 63;
  const int w    = t >> 6;        // 0..15 -> oc w*16
  const int n    = lane & 15;
  const int g    = lane >> 4;

  // B frag (step s): gB + s*16384 ; wave reads 1KB contiguous
  const char* gB = (const char*)wt + (w*16 + n)*64 + g*16;
  bhalf8 bb[4];                   // distance-4 slots (static idx after unroll)
#pragma unroll
  for (int ss = 0; ss < 4; ++ss)
    bb[ss] = *(const bhalf8*)(gB + ss*16384);

  // ---- stage 2 images: chunk c of pixel p -> slot (c + p/2 + p/32)&15 ----
  for (int i = t; i < 7200; i += 1024) {
    int img = (i >= 3600);
    int r = i - img*3600;
    int p = r >> 4, c = r & 15;
    uint4 v = *(const uint4*)((const char*)a +
              (((size_t)(b0+img)*225 + p)*256 + c*16));
    int csw = (c + (p >> 1) + (p >> 5)) & 15;
    *(uint4*)((char*)Il + ((img*225 + p)*136 + csw*8)*2) = v;
  }

  // ---- per-lane M geometry ----
  int rowb[5], pixb[5];
#pragma unroll
  for (int mt = 0; mt < 5; ++mt) {
    int m  = mt*16 + n;
    int mm = (m < 72) ? m : 0;
    int img = (mm >= 36);
    int pos = mm - img*36;
    int py = pos/6, px = pos - py*6;
    pixb[mt] = 30*py + 2*px;
    rowb[mt] = img*225*136;
  }

  floatx4 acc[5];
#pragma unroll
  for (int mt = 0; mt < 5; ++mt) acc[mt] = (floatx4){0.f, 0.f, 0.f, 0.f};

  __syncthreads();   // Il staged; the ONLY barrier

  int s = 0;
#pragma unroll 1
  for (int ky = 0; ky < 5; ++ky) {
#pragma unroll 1
    for (int kx = 0; kx < 5; ++kx) {
      const int dpix = ky*15 + kx;
      int prow[5], pqv[5];
#pragma unroll
      for (int mt = 0; mt < 5; ++mt) {
        int p = pixb[mt] + dpix;
        prow[mt] = rowb[mt] + p*136;
        pqv[mt]  = (p >> 1) + (p >> 5);
      }
#pragma unroll
      for (int icq = 0; icq < 4; ++icq) {
        const int scur = s + icq;
#pragma unroll
        for (int mt = 0; mt < 5; ++mt) {
          int csw = ((icq*4 + g) + pqv[mt]) & 15;
          bhalf8 af = *(const bhalf8*)((const char*)Il +
                       (prow[mt] + csw*8)*2);
          acc[mt] = __builtin_amdgcn_mfma_f32_16x16x32_bf16(
              af, bb[icq], acc[mt], 0, 0, 0);
        }
        {
          const int spre = (scur + 4 <= 99) ? (scur + 4) : 99;
          bb[icq] = *(const bhalf8*)(gB + spre*16384);
        }
      }
      s += 4;
    }
  }

  // ---- epilogue: D row=g*4+r (m), col=n. write bf16 [img][pos][oc] ----
  const float bv = bias[w*16 + n];
#pragma unroll
  for (int mt = 0; mt < 5; ++mt) {
#pragma unroll
    for (int r = 0; r < 4; ++r) {
      int m = mt*16 + g*4 + r;
      if (m < 72) {
        int img = (m >= 36);
        int pos = m - img*36;
        out[(((size_t)(b0+img)*36 + pos)*256 + w*16 + n)] =
            __float2bfloat16(fmaxf(acc[mt][r] + bv, 0.f));
      }
    }
  }
}

// ============================================================================
// conv3_mfma (split-K): h2t -> fp32 partials pout[8][1024][256][4].
// grid (64 img-groups of 16, 8 ic-slices of 32). Per block: M=64, N=256,
// K=800 (25 taps x 32 ic). 512 thr = 8 waves; wave = 4 Mt x 2 Nt ->
// 8 MFMA / wave / tap (4x old density). A-LDS 46 KB -> 2 blocks/CU =
// 4 waves/SIMD. B register distance-2 (2 static slot sets). No bias/ReLU
// here — caps sums the 8 partials + bias + ReLU.
// ============================================================================
__global__ __launch_bounds__(512) void conv3_mfma_kernel(
    const __hip_bfloat16* __restrict__ a,   // h2t [1024][36][256]
    const __hip_bfloat16* __restrict__ wt,  // wt3 dense [100][256][64]
    float* __restrict__ pout)               // [8][1024*1024]
{
  __shared__ __align__(16) unsigned short Il[16*1448];    // 46,336 B
  const int b0   = blockIdx.x * 16;
  const int kq   = blockIdx.y;             // ic slice kq*32..+31
  const int t    = threadIdx.x;
  const int lane = t & 63;
  const int w    = t >> 6;                 // 0..7 -> oc w*32
  const int n    = lane & 15;
  const int g    = lane >> 4;

  // ---- stage A: 16 img x 36 pix x 32-ic slice (row stride 40 elems) ----
  for (int i = t; i < 2304; i += 512) {    // 16*36*4 chunks of 16B
    int img = i / 144, r = i - img*144;
    int p = r >> 2, c = r & 3;
    uint4 v = *(const uint4*)((const char*)a +
              ((((size_t)(b0+img)*36 + p) << 9) + kq*64 + c*16));
    *(uint4*)((char*)Il + (img*1448 + p*40 + c*8)*2) = v;
  }

  // ---- B: dense wt3, slice rows s' = tap*4 + kq/2, offset (kq&1)*32 ----
  const char* gB = (const char*)wt + (size_t)(w*32 + n)*128 +
                   (kq & 1)*64 + g*16;
  const int kqs = kq >> 1;
  bhalf8 b00, b01, b10, b11;               // 2 slot sets (static, R5 lesson)
  b00 = *(const bhalf8*)(gB + (size_t)(0*4 + kqs)*32768);
  b01 = *(const bhalf8*)(gB + (size_t)(0*4 + kqs)*32768 + 2048);
  b10 = *(const bhalf8*)(gB + (size_t)(1*4 + kqs)*32768);
  b11 = *(const bhalf8*)(gB + (size_t)(1*4 + kqs)*32768 + 2048);

  // ---- per-lane A bases ----
  const int d = n >> 2, pos = n & 3;
  const int pb = (pos >> 1)*6 + (pos & 1);   // base pixel of this position
  int ab[4];
#pragma unroll
  for (int mt = 0; mt < 4; ++mt)
    ab[mt] = ((mt*4 + d)*1448 + pb*40 + g*8) * 2;   // bytes

  floatx4 acc[4][2];
#pragma unroll
  for (int mt = 0; mt < 4; ++mt)
#pragma unroll
    for (int nt = 0; nt < 2; ++nt)
      acc[mt][nt] = (floatx4){0.f, 0.f, 0.f, 0.f};

  __syncthreads();   // the ONLY barrier

  int toff = 0, kx = 0;    // tapoff = ky*6+kx, tracked incrementally
#pragma unroll 1
  for (int tap = 0; tap < 24; tap += 2) {
    // ---- even tap: slot set 0 ----
#pragma unroll
    for (int mt = 0; mt < 4; ++mt) {
      bhalf8 av = *(const bhalf8*)((const char*)Il + ab[mt] + toff*80);
      acc[mt][0] = __builtin_amdgcn_mfma_f32_16x16x32_bf16(av, b00, acc[mt][0], 0, 0, 0);
      acc[mt][1] = __builtin_amdgcn_mfma_f32_16x16x32_bf16(av, b01, acc[mt][1], 0, 0, 0);
    }
    b00 = *(const bhalf8*)(gB + (size_t)((tap+2)*4 + kqs)*32768);
    b01 = *(const bhalf8*)(gB + (size_t)((tap+2)*4 + kqs)*32768 + 2048);
    if (++kx == 5) { kx = 0; toff += 2; } else ++toff;
    // ---- odd tap: slot set 1 ----
#pragma unroll
    for (int mt = 0; mt < 4; ++mt) {
      bhalf8 av = *(const bhalf8*)((const char*)Il + ab[mt] + toff*80);
      acc[mt][0] = __builtin_amdgcn_mfma_f32_16x16x32_bf16(av, b10, acc[mt][0], 0, 0, 0);
      acc[mt][1] = __builtin_amdgcn_mfma_f32_16x16x32_bf16(av, b11, acc[mt][1], 0, 0, 0);
    }
    {
      const int tpre = (tap + 3 <= 24) ? (tap + 3) : 24;
      b10 = *(const bhalf8*)(gB + (size_t)(tpre*4 + kqs)*32768);
      b11 = *(const bhalf8*)(gB + (size_t)(tpre*4 + kqs)*32768 + 2048);
    }
    if (++kx == 5) { kx = 0; toff += 2; } else ++toff;
  }
  // ---- tail tap 24 (toff = 28): slot set 0 ----
#pragma unroll
  for (int mt = 0; mt < 4; ++mt) {
    bhalf8 av = *(const bhalf8*)((const char*)Il + ab[mt] + toff*80);
    acc[mt][0] = __builtin_amdgcn_mfma_f32_16x16x32_bf16(av, b00, acc[mt][0], 0, 0, 0);
    acc[mt][1] = __builtin_amdgcn_mfma_f32_16x16x32_bf16(av, b01, acc[mt][1], 0, 0, 0);
  }

  // ---- epilogue: raw fp32 partials [img][oc][pos] ----
  float* po = pout + (size_t)kq*1048576;
#pragma unroll
  for (int mt = 0; mt < 4; ++mt) {
#pragma unroll
    for (int r = 0; r < 4; ++r) {
      int m = mt*16 + g*4 + r;
      int img = m >> 2, p2 = m & 3;
#pragma unroll
      for (int nt = 0; nt < 2; ++nt)
        po[((size_t)(b0+img)*256 + w*32 + nt*16 + n)*4 + p2] = acc[mt][nt][r];
    }
  }
}

// ============================================================================
// caps: sum 8 conv3 partials + bias + ReLU -> squash -> u_hat -> routing
// -> v_lengths + fused fc1
// ============================================================================
__global__ __launch_bounds__(256) void caps_kernel(
    const float* __restrict__ pout, const __hip_bfloat16* __restrict__ cwt,
    const float* __restrict__ cb, const float* __restrict__ c3b,
    const int* __restrict__ y,
    const float* __restrict__ fc1wt, const float* __restrict__ fc1b,
    float* __restrict__ vlen, __hip_bfloat16* __restrict__ h1f)
{
  __shared__ float prim[1024];     // [64][16]
  __shared__ float uh[10240];      // [64][10][16]
  __shared__ float bij[640];
  __shared__ float cij[640];
  __shared__ float vv[160];        // [10][16]
  const int b = blockIdx.x, t = threadIdx.x;
  {
    const float* pp = pout + (size_t)b*1024 + t*4;
    float4 s4 = *(const float4*)pp;
#pragma unroll
    for (int q = 1; q < 8; ++q) {
      float4 v = *(const float4*)(pp + (size_t)q*1048576);
      s4.x += v.x; s4.y += v.y; s4.z += v.z; s4.w += v.w;
    }
    const float bv = c3b[t];       // oc = t
    float4 h = make_float4(fmaxf(s4.x + bv, 0.f), fmaxf(s4.y + bv, 0.f),
                           fmaxf(s4.z + bv, 0.f), fmaxf(s4.w + bv, 0.f));
    float dd = h.x*h.x + h.y*h.y + h.z*h.z + h.w*h.w;
    dd += __shfl_xor(dd, 1);
    dd += __shfl_xor(dd, 2);
    float sc = dd / (1.f + dd) / sqrtf(dd + EPSF);
    float4 o4 = make_float4(h.x*sc, h.y*sc, h.z*sc, h.w*sc);
    *(float4*)&prim[t*4] = o4;     // prim flat elem = t*4..t*4+3
  }
  for (int f = t; f < 640; f += 256) bij[f] = 0.f;
  __syncthreads();
  for (int f = t; f < 10240; f += 256) {
    const int i = f / 160;
    const uint4* wv = (const uint4*)(cwt + (size_t)f*16);
    uint4 wa = wv[0], wb = wv[1];
    unsigned uw[8] = {wa.x, wa.y, wa.z, wa.w, wb.x, wb.y, wb.z, wb.w};
    const float* pp = prim + i*16;
    float s = 0.f;
#pragma unroll
    for (int q = 0; q < 8; ++q) {
      float lo = __uint_as_float(uw[q] << 16);
      float hi = __uint_as_float(uw[q] & 0xffff0000u);
      s = fmaf(pp[2*q],   lo, s);
      s = fmaf(pp[2*q+1], hi, s);
    }
    uh[f] = s;
  }
  __syncthreads();
  for (int r = 0; r < 3; ++r) {
    if (t < 64) {
      float e[10];
      float mx = -1e30f;
#pragma unroll
      for (int o = 0; o < 10; ++o) { e[o] = bij[t*10 + o]; mx = fmaxf(mx, e[o]); }
      float sum = 0.f;
#pragma unroll
      for (int o = 0; o < 10; ++o) { e[o] = expf(e[o] - mx); sum += e[o]; }
      float inv = 1.f / sum;
#pragma unroll
      for (int o = 0; o < 10; ++o) cij[t*10 + o] = e[o] * inv;
    }
    __syncthreads();
    if (t < 160) {
      const int o = t >> 4;
      float s = cb[t];
      for (int i = 0; i < 64; ++i) s = fmaf(cij[i*10 + o], uh[i*160 + t], s);
      float dd = s*s;
      dd += __shfl_xor(dd, 1); dd += __shfl_xor(dd, 2);
      dd += __shfl_xor(dd, 4); dd += __shfl_xor(dd, 8);
      float sc = dd / (1.f + dd) / sqrtf(dd + EPSF);
      vv[t] = s * sc;
      if (r == 2 && (t & 15) == 0)
        vlen[b*10 + o] = sqrtf(sc*sc*dd + EPSF);
    }
    __syncthreads();
    if (r < 2) {
      for (int f = t; f < 640; f += 256) {
        int i = f / 10, o = f % 10;
        const float* up = &uh[i*160 + o*16];
        const float* vp = &vv[o*16];
        float a = 0.f;
#pragma unroll
        for (int j = 0; j < 16; ++j) a = fmaf(up[j], vp[j], a);
        bij[f] += a;
      }
      __syncthreads();
    }
  }
  const int yb = y[b];
  const float* vy = &vv[yb*16];
  for (int nn = t; nn < 512; nn += 256) {
    float s = fc1b[nn];
#pragma unroll
    for (int k = 0; k < 16; ++k)
      s = fmaf(vy[k], fc1wt[(yb*16 + k)*512 + nn], s);
    h1f[b*512 + nn] = __float2bfloat16(fmaxf(s, 0.f));
  }
}

// ============================================================================
// fc_mfma: out = act(A[M,K]bf16 @ W[N,K]bf16^T + bias). Pure-register GEMM,
// two statically-indexed register sets (R5 scratch-demotion lesson).
// ============================================================================
template<int ACT, int MT, int NT>
__global__ __launch_bounds__(256) void fc_mfma_kernel(
    const __hip_bfloat16* __restrict__ A,   // [M,K]
    const __hip_bfloat16* __restrict__ W,   // [N,K]
    const float* __restrict__ bias,
    void* __restrict__ outv, int M, int N, int K)
{
  const int t    = threadIdx.x;
  const int lane = t & 63;
  const int w    = t >> 6;
  const int wr   = w >> 1, wc = w & 1;
  const int n    = lane & 15, g = lane >> 4;
  const int m0   = blockIdx.x * (2*MT*16) + wr*(MT*16);
  const int n0   = blockIdx.y * (2*NT*16) + wc*(NT*16);
  const __hip_bfloat16* Ap = A + (size_t)(m0 + n)*K + g*8;
  const __hip_bfloat16* Wp = W + (size_t)(n0 + n)*K + g*8;
  const int steps = K >> 5;

  bhalf8 aa0[MT], aa1[MT], bb0[NT], bb1[NT];
#pragma unroll
  for (int mt = 0; mt < MT; ++mt) {
    aa0[mt] = *(const bhalf8*)(Ap + (size_t)mt*16*K);
    aa1[mt] = *(const bhalf8*)(Ap + (size_t)mt*16*K + 32);
  }
#pragma unroll
  for (int nt = 0; nt < NT; ++nt) {
    bb0[nt] = *(const bhalf8*)(Wp + (size_t)nt*16*K);
    bb1[nt] = *(const bhalf8*)(Wp + (size_t)nt*16*K + 32);
  }

  floatx4 acc[MT][NT];
#pragma unroll
  for (int mt = 0; mt < MT; ++mt)
#pragma unroll
    for (int nt = 0; nt < NT; ++nt)
      acc[mt][nt] = (floatx4){0.f, 0.f, 0.f, 0.f};

#pragma unroll 1
  for (int s = 0; s < steps; s += 2) {
#pragma unroll
    for (int mt = 0; mt < MT; ++mt)
#pragma unroll
      for (int nt = 0; nt < NT; ++nt)
        acc[mt][nt] = __builtin_amdgcn_mfma_f32_16x16x32_bf16(
            aa0[mt], bb0[nt], acc[mt][nt], 0, 0, 0);
    {
      const int spre = (s + 2 < steps) ? (s + 2) : s;
#pragma unroll
      for (int mt = 0; mt < MT; ++mt)
        aa0[mt] = *(const bhalf8*)(Ap + (size_t)mt*16*K + spre*32);
#pragma unroll
      for (int nt = 0; nt < NT; ++nt)
        bb0[nt] = *(const bhalf8*)(Wp + (size_t)nt*16*K + spre*32);
    }
#pragma unroll
    for (int mt = 0; mt < MT; ++mt)
#pragma unroll
      for (int nt = 0; nt < NT; ++nt)
        acc[mt][nt] = __builtin_amdgcn_mfma_f32_16x16x32_bf16(
            aa1[mt], bb1[nt], acc[mt][nt], 0, 0, 0);
    {
      const int spre = (s + 3 < steps) ? (s + 3) : (s + 1);
#pragma unroll
      for (int mt = 0; mt < MT; ++mt)
        aa1[mt] = *(const bhalf8*)(Ap + (size_t)mt*16*K + spre*32);
#pragma unroll
      for (int nt = 0; nt < NT; ++nt)
        bb1[nt] = *(const bhalf8*)(Wp + (size_t)nt*16*K + spre*32);
    }
  }

#pragma unroll
  for (int mt = 0; mt < MT; ++mt) {
#pragma unroll
    for (int r = 0; r < 4; ++r) {
      const int m = m0 + mt*16 + g*4 + r;
#pragma unroll
      for (int nt = 0; nt < NT; ++nt) {
        const int col = n0 + nt*16 + n;
        float v = acc[mt][nt][r] + bias[col];
        if (ACT == 0) {
          ((__hip_bfloat16*)outv)[(size_t)m*N + col] =
              __float2bfloat16(fmaxf(v, 0.f));
        } else {
          ((float*)outv)[(size_t)m*N + col] = 1.f / (1.f + expf(-v));
        }
      }
    }
  }
}

// ============================================================================
extern "C" void kernel_launch(void* const* d_in, const int* in_sizes, int n_in,
                              void* d_out, int out_size, void* d_ws, size_t ws_size,
                              hipStream_t stream) {
  const float* x       = (const float*)d_in[0];
  const int*   y       = (const int*)  d_in[1];
  const float* conv1_w = (const float*)d_in[2];
  const float* conv1_b = (const float*)d_in[3];
  const float* conv2_w = (const float*)d_in[4];
  const float* conv2_b = (const float*)d_in[5];
  const float* conv3_w = (const float*)d_in[6];
  const float* conv3_b = (const float*)d_in[7];
  const float* caps_w  = (const float*)d_in[8];
  const float* caps_b  = (const float*)d_in[9];
  const float* fc1_w   = (const float*)d_in[10];
  const float* fc1_b   = (const float*)d_in[11];
  const float* fc2_w   = (const float*)d_in[12];
  const float* fc2_b   = (const float*)d_in[13];
  const float* fc3_w   = (const float*)d_in[14];
  const float* fc3_b   = (const float*)d_in[15];
  float* out = (float*)d_out;
  float* ws  = (float*)d_ws;

  // ws layout (float units), total 31,866,880 floats = 127.5 MB
  __hip_bfloat16* h1t   = (__hip_bfloat16*)ws;                // 29,491,200 bf16
  __hip_bfloat16* wt2   = (__hip_bfloat16*)(ws + 14745600);   //    819,200 bf16
  __hip_bfloat16* wt3   = (__hip_bfloat16*)(ws + 15155200);   //  1,638,400 bf16
  __hip_bfloat16* h2t   = (__hip_bfloat16*)(ws + 15974400);   //  9,437,184 bf16
  float*          pout  = ws + 20692992;                      //  8,388,608 f32
  __hip_bfloat16* h1f   = (__hip_bfloat16*)(ws + 29081600);   //    524,288 bf16
  __hip_bfloat16* h2f   = (__hip_bfloat16*)(ws + 29343744);   //  1,048,576 bf16
  __hip_bfloat16* wf2   = (__hip_bfloat16*)(ws + 29868032);   //    524,288 bf16
  __hip_bfloat16* wf3   = (__hip_bfloat16*)(ws + 30130176);   //  3,145,728 bf16
  __hip_bfloat16* cwt   = (__hip_bfloat16*)(ws + 31703040);   //    163,840 bf16
  float*          fc1wt = ws + 31784960;                      //     81,920 f32

  wtrans_kernel     <<<dim3(3200),  256, 0, stream>>>(conv2_w, wt2);
  wtrans3_kernel    <<<dim3(6400),  256, 0, stream>>>(conv3_w, wt3);
  wtrans_caps_kernel<<<dim3(640),   256, 0, stream>>>(caps_w, cwt);
  wtrans_fc1_kernel <<<dim3(320),   256, 0, stream>>>(fc1_w, fc1wt);
  cast_bf16_kernel  <<<dim3(2048),  256, 0, stream>>>(fc2_w, wf2, 524288);
  cast_bf16_kernel  <<<dim3(12288), 256, 0, stream>>>(fc3_w, wf3, 3145728);
  conv1_kernel<<<dim3(1024),       256, 0, stream>>>(x, conv1_w, conv1_b, h1t);
  conv2_mfma_kernel<<<dim3(512),  1024, 0, stream>>>(h1t, wt2, conv2_b, h2t);
  conv3_mfma_kernel<<<dim3(64, 8), 512, 0, stream>>>(h2t, wt3, pout);
  caps_kernel<<<dim3(1024),        256, 0, stream>>>(pout, cwt, caps_b, conv3_b,
                                                     y, fc1wt, fc1_b, out, h1f);
  fc_mfma_kernel<0,2,2><<<dim3(16, 16), 256, 0, stream>>>(
      h1f, wf2, fc2_b, h2f, 1024, 1024, 512);
  fc_mfma_kernel<1,2,2><<<dim3(16, 48), 256, 0, stream>>>(
      h2f, wf3, fc3_b, out + 10240, 1024, 3072, 1024);
}